// Round 4
// baseline (357.679 us; speedup 1.0000x reference)
//
#include <hip/hip_runtime.h>
#include <hip/hip_bf16.h>

typedef unsigned long long u64;
typedef float f32x4 __attribute__((ext_vector_type(4)));

#define H_SZ 4096
#define NBITS 16
#define NFEAT 128
#define NCLS 10
#define THETA 8

// Bit-packing convention: for a chunk c of 256 positions, act word (c,j),
// j=0..3, has bit i <-> position p = c*256 + 4*i + j. This is exactly what
// per-component ballots of a lane-major float4 load produce.

// ---------------------------------------------------------------------------
// 64x64 bit-matrix transpose across the 64 lanes (6 butterfly stages).
// In: lane l holds row l (bit b = M[l][b]). Out: lane l holds column l.
// ---------------------------------------------------------------------------
__device__ __forceinline__ u64 bfly_stage(u64 x, int lane, int d, u64 Md) {
    u64 p = __shfl_xor(x, d);
    return (lane & d) ? ((x & Md) | ((p >> d) & ~Md))
                      : ((x & ~Md) | ((p << d) & Md));
}

__device__ __forceinline__ u64 transpose64(u64 x, int lane) {
    x = bfly_stage(x, lane, 32, 0xFFFFFFFF00000000ULL);
    x = bfly_stage(x, lane, 16, 0xFFFF0000FFFF0000ULL);
    x = bfly_stage(x, lane,  8, 0xFF00FF00FF00FF00ULL);
    x = bfly_stage(x, lane,  4, 0xF0F0F0F0F0F0F0F0ULL);
    x = bfly_stage(x, lane,  2, 0xCCCCCCCCCCCCCCCCULL);
    x = bfly_stage(x, lane,  1, 0xAAAAAAAAAAAAAAAAULL);
    return x;
}

// ---------------------------------------------------------------------------
// One chunk (256 positions) of the segment sums: 8 ballots -> wave-uniform
// pos/neg masks, AND with act words (p[0],p[64],p[128],p[192]), popcount.
// ---------------------------------------------------------------------------
__device__ __forceinline__ void chunk_accum(f32x4 a, f32x4 b, const u64* p,
                                            unsigned& zp0, unsigned& zn0,
                                            unsigned& zp1, unsigned& zn1) {
    u64 A0 = p[0], A1 = p[64], A2 = p[128], A3 = p[192];
    u64 m;
    m = __ballot(a.x > 0.0f); zp0 += __builtin_popcountll(A0 & m);
    m = __ballot(a.x < 0.0f); zn0 += __builtin_popcountll(A0 & m);
    m = __ballot(a.y > 0.0f); zp0 += __builtin_popcountll(A1 & m);
    m = __ballot(a.y < 0.0f); zn0 += __builtin_popcountll(A1 & m);
    m = __ballot(a.z > 0.0f); zp0 += __builtin_popcountll(A2 & m);
    m = __ballot(a.z < 0.0f); zn0 += __builtin_popcountll(A2 & m);
    m = __ballot(a.w > 0.0f); zp0 += __builtin_popcountll(A3 & m);
    m = __ballot(a.w < 0.0f); zn0 += __builtin_popcountll(A3 & m);

    m = __ballot(b.x > 0.0f); zp1 += __builtin_popcountll(A0 & m);
    m = __ballot(b.x < 0.0f); zn1 += __builtin_popcountll(A0 & m);
    m = __ballot(b.y > 0.0f); zp1 += __builtin_popcountll(A1 & m);
    m = __ballot(b.y < 0.0f); zn1 += __builtin_popcountll(A1 & m);
    m = __ballot(b.z > 0.0f); zp1 += __builtin_popcountll(A2 & m);
    m = __ballot(b.z < 0.0f); zn1 += __builtin_popcountll(A2 & m);
    m = __ballot(b.w > 0.0f); zp1 += __builtin_popcountll(A3 & m);
    m = __ballot(b.w < 0.0f); zn1 += __builtin_popcountll(A3 & m);
}

// Full segment-sum loop for one neuron h (both segments interleaved):
// first 4 chunks come from the pre-peeled registers, rest streamed NT.
// Returns fired ballot (bit = batch).
template <int NC>
__device__ __forceinline__ u64 layer_accum(const f32x4* w0, const f32x4* w1,
                                           const f32x4 pa[4], const f32x4 pb[4],
                                           const u64* lds, int lane) {
    unsigned zp0 = 0, zn0 = 0, zp1 = 0, zn1 = 0;
    #pragma unroll
    for (int c = 0; c < 4; c++)
        chunk_accum(pa[c], pb[c], lds + c * 256 + lane, zp0, zn0, zp1, zn1);
    #pragma unroll 4
    for (int c = 4; c < NC; c++) {
        f32x4 a = __builtin_nontemporal_load(w0 + c * 64);
        f32x4 b = __builtin_nontemporal_load(w1 + c * 64);
        chunk_accum(a, b, lds + c * 256 + lane, zp0, zn0, zp1, zn1);
    }
    int z0 = (int)zp0 - (int)zn0;
    int z1 = (int)zp1 - (int)zn1;
    return __ballot(z0 >= THETA) | __ballot(z1 >= THETA);
}

// ---------------------------------------------------------------------------
// Layer 0: encode fused in-LDS (hidden under peeled W0 loads) + segment sums.
// Block 0 also zeroes out[] (stream order puts this before output_kernel).
// grid: 1024 blocks x 256 thr; wave = neuron h (2 segments).
// ---------------------------------------------------------------------------
__global__ __launch_bounds__(256, 4) void layer0_kernel(
    const float* __restrict__ x, const float* __restrict__ W0,
    u64* __restrict__ fired0, float* __restrict__ out, int out_n)
{
    __shared__ __align__(16) u64 lds[32 * 64];   // 16 KB (P0 = 2048)
    int tid = threadIdx.x;
    int lane = tid & 63;
    int warp = tid >> 6;
    int h = blockIdx.x * 4 + warp;               // 0..4095

    const f32x4* w0 = (const f32x4*)(W0 + (size_t)(2 * h) * 2048) + lane;
    const f32x4* w1 = (const f32x4*)(W0 + (size_t)(2 * h + 1) * 2048) + lane;
    f32x4 pa[4], pb[4];
    #pragma unroll
    for (int c = 0; c < 4; c++) {
        pa[c] = __builtin_nontemporal_load(w0 + c * 64);
        pb[c] = __builtin_nontemporal_load(w1 + c * 64);
    }

    if (blockIdx.x == 0)                          // zero out[] before output
        for (int i = tid; i < out_n; i += 256)    //  kernel (stream order)
            out[i] = 0.0f;

    // Encode: thread (j=warp, b=lane) builds words (c=0..7, j, b) from x row b.
    // i = 16q+4e+m -> p = c*256+4i+j -> f = 16c+4q+e, t = 4m+j,
    // thr = (t+1)/(NBITS+1) — identical fp32 math to ref.
    {
        float thr0 = (4 * 0 + warp + 1.0f) / (NBITS + 1.0f);
        float thr1 = (4 * 1 + warp + 1.0f) / (NBITS + 1.0f);
        float thr2 = (4 * 2 + warp + 1.0f) / (NBITS + 1.0f);
        float thr3 = (4 * 3 + warp + 1.0f) / (NBITS + 1.0f);
        const f32x4* xb = (const f32x4*)(x + lane * NFEAT);
        #pragma unroll
        for (int c = 0; c < 8; c++) {
            u64 word = 0;
            #pragma unroll
            for (int q = 0; q < 4; q++) {
                f32x4 v = xb[c * 4 + q];
                int base = q * 16;
                word |= (u64)(v.x >= thr0) << (base + 0);
                word |= (u64)(v.x >= thr1) << (base + 1);
                word |= (u64)(v.x >= thr2) << (base + 2);
                word |= (u64)(v.x >= thr3) << (base + 3);
                word |= (u64)(v.y >= thr0) << (base + 4);
                word |= (u64)(v.y >= thr1) << (base + 5);
                word |= (u64)(v.y >= thr2) << (base + 6);
                word |= (u64)(v.y >= thr3) << (base + 7);
                word |= (u64)(v.z >= thr0) << (base + 8);
                word |= (u64)(v.z >= thr1) << (base + 9);
                word |= (u64)(v.z >= thr2) << (base + 10);
                word |= (u64)(v.z >= thr3) << (base + 11);
                word |= (u64)(v.w >= thr0) << (base + 12);
                word |= (u64)(v.w >= thr1) << (base + 13);
                word |= (u64)(v.w >= thr2) << (base + 14);
                word |= (u64)(v.w >= thr3) << (base + 15);
            }
            lds[(c * 4 + warp) * 64 + lane] = word;
        }
    }
    __syncthreads();
    u64 f0 = layer_accum<8>(w0, w1, pa, pb, lds, lane);
    if (lane == 0) fired0[h] = f0;
}

// ---------------------------------------------------------------------------
// Layers 1/2: staging = in-block 64x64 butterfly transpose of the previous
// layer's fired[] (warp w builds j=w words: IN[lane] = fired[c*256+4*lane+w]),
// hidden under the peeled weight loads.
// grid: 1024 blocks x 256 thr; wave = neuron h (2 segments).
// ---------------------------------------------------------------------------
__global__ __launch_bounds__(256, 4) void layerN_kernel(
    const float* __restrict__ W, const u64* __restrict__ fired_in,
    u64* __restrict__ fired_out)
{
    __shared__ __align__(16) u64 lds[64 * 64];   // 32 KB (P = 4096)
    int tid = threadIdx.x;
    int lane = tid & 63;
    int warp = tid >> 6;
    int h = blockIdx.x * 4 + warp;               // 0..4095

    const f32x4* w0 = (const f32x4*)(W + (size_t)(2 * h) * 4096) + lane;
    const f32x4* w1 = (const f32x4*)(W + (size_t)(2 * h + 1) * 4096) + lane;
    f32x4 pa[4], pb[4];
    #pragma unroll
    for (int c = 0; c < 4; c++) {
        pa[c] = __builtin_nontemporal_load(w0 + c * 64);
        pb[c] = __builtin_nontemporal_load(w1 + c * 64);
    }

    #pragma unroll 4
    for (int c = 0; c < 16; c++) {               // warp w builds j=w words
        u64 xw = fired_in[c * 256 + 4 * lane + warp];
        xw = transpose64(xw, lane);
        lds[(c * 4 + warp) * 64 + lane] = xw;
    }
    __syncthreads();
    u64 f = layer_accum<16>(w0, w1, pa, pb, lds, lane);
    if (lane == 0) fired_out[h] = f;
}

// ---------------------------------------------------------------------------
// Output: out[b,c] = sum_l sum_h fired_l[b,h] * outW[l,h,c]; lane = batch.
// Block-uniform (l,c); 4 wave-partials reduce in LDS -> 1 atomic per
// (block, lane). grid: 480 blocks x 256 thr (3 x 10 x 64 chunks of 64 h).
// ---------------------------------------------------------------------------
__global__ void output_kernel(const float* __restrict__ outW,
                              const u64* __restrict__ fired,
                              float* __restrict__ out) {
    __shared__ float red[4][64];
    int tid = threadIdx.x;
    int lane = tid & 63;
    int warp = tid >> 6;
    int wid = blockIdx.x * 4 + warp;   // 0..1919
    int l = wid / (NCLS * 64);
    int rem = wid % (NCLS * 64);
    int c = rem / 64;
    int chunk = rem % 64;
    const u64* fl = fired + l * H_SZ;
    int h0 = chunk * 64;
    float acc = 0.0f;
    #pragma unroll 8
    for (int h = h0; h < h0 + 64; h++) {
        float wv = outW[((size_t)(l * H_SZ + h)) * NCLS + c];
        if ((fl[h] >> lane) & 1ULL) acc += wv;
    }
    red[warp][lane] = acc;
    __syncthreads();
    if (warp == 0) {
        float s = red[0][lane] + red[1][lane] + red[2][lane] + red[3][lane];
        atomicAdd(&out[lane * NCLS + c], s);
    }
}

// ---------------------------------------------------------------------------
extern "C" void kernel_launch(void* const* d_in, const int* in_sizes, int n_in,
                              void* d_out, int out_size, void* d_ws, size_t ws_size,
                              hipStream_t stream) {
    const float* x    = (const float*)d_in[0];
    const float* W0   = (const float*)d_in[1];
    const float* W1   = (const float*)d_in[2];
    const float* W2   = (const float*)d_in[3];
    const float* outW = (const float*)d_in[4];
    float* out = (float*)d_out;

    u64* fired = (u64*)d_ws;                     // 3*4096 u64 = 96 KB

    layer0_kernel<<<1024, 256, 0, stream>>>(x, W0, fired, out, out_size);
    layerN_kernel<<<1024, 256, 0, stream>>>(W1, fired, fired + H_SZ);
    layerN_kernel<<<1024, 256, 0, stream>>>(W2, fired + H_SZ, fired + 2 * H_SZ);
    output_kernel<<<480, 256, 0, stream>>>(outW, fired, out);
}